// Round 2
// baseline (2188.269 us; speedup 1.0000x reference)
//
#include <hip/hip_runtime.h>
#include <stdint.h>

typedef unsigned short u16;

#define BATCH   4
#define CH      256
#define NPIX    4096      // 64*64
#define NGROUPS 32
#define CPG     8         // channels per group
#define QKV_O   768
#define EPS     1e-5f

#define TQ 32
#define TK 32
#define QSTRIDE 264       // bf16 elems per LDS row (256 + 8 pad, keeps 16B align)

// ---------- bf16 helpers ----------
__device__ __forceinline__ float bf2f(u16 u) {
    union { uint32_t i; float f; } v; v.i = ((uint32_t)u) << 16; return v.f;
}
__device__ __forceinline__ u16 f2bf(float f) {
    union { float f; uint32_t i; } v; v.f = f;
    uint32_t x = v.i;
    uint32_t r = (x + 0x7fffu + ((x >> 16) & 1u)) >> 16;
    return (u16)r;
}
__device__ __forceinline__ void unpack2(uint32_t u, float& a, float& b) {
    union { uint32_t i; float f; } lo, hi;
    lo.i = u << 16; hi.i = u & 0xffff0000u;
    a = lo.f; b = hi.f;
}
__device__ __forceinline__ void unpack8(uint4 u, float* f) {
    unpack2(u.x, f[0], f[1]); unpack2(u.y, f[2], f[3]);
    unpack2(u.z, f[4], f[5]); unpack2(u.w, f[6], f[7]);
}

// ---------- runtime input-dtype detection ----------
// bf16 stream: even u16s are bf16 of N(0,1) samples -> exponent field sane.
// fp32 stream: even u16s are low mantissa halves -> ~uniform random bits.
__device__ __forceinline__ bool detect_f32(const void* xv) {
    const u16* p = (const u16*)xv;
    int bad = 0;
    #pragma unroll
    for (int i = 0; i < 32; i++) {
        u16 v = p[2 * i];
        int e = (v >> 7) & 0xff;
        bad += (e < 0x68 || e > 0x90) ? 1 : 0;
    }
    return bad >= 10;
}

// ---------- dual-dtype load/store helpers (elem_off in elements) ----------
__device__ __forceinline__ float load1(const void* b, size_t i, bool f32) {
    return f32 ? ((const float*)b)[i] : bf2f(((const u16*)b)[i]);
}
__device__ __forceinline__ void load4v(const void* base, size_t off, bool f32, float* f) {
    if (f32) {
        float4 a = *(const float4*)((const float*)base + off);
        f[0] = a.x; f[1] = a.y; f[2] = a.z; f[3] = a.w;
    } else {
        uint2 u = *(const uint2*)((const u16*)base + off);
        unpack2(u.x, f[0], f[1]); unpack2(u.y, f[2], f[3]);
    }
}
__device__ __forceinline__ void load8v(const void* base, size_t off, bool f32, float* f) {
    if (f32) {
        const float4* p = (const float4*)((const float*)base + off);
        float4 a = p[0], b = p[1];
        f[0] = a.x; f[1] = a.y; f[2] = a.z; f[3] = a.w;
        f[4] = b.x; f[5] = b.y; f[6] = b.z; f[7] = b.w;
    } else {
        uint4 u = *(const uint4*)((const u16*)base + off);
        unpack8(u, f);
    }
}
__device__ __forceinline__ void store4v(void* base, size_t off, bool f32, const float* f) {
    if (f32) {
        *(float4*)((float*)base + off) = make_float4(f[0], f[1], f[2], f[3]);
    } else {
        union { uint2 v; u16 s[4]; } pk;
        #pragma unroll
        for (int j = 0; j < 4; j++) pk.s[j] = f2bf(f[j]);
        *(uint2*)((u16*)base + off) = pk.v;
    }
}

// ---------- K1: GroupNorm stats: mean + rstd per (b, group) ----------
__global__ __launch_bounds__(256) void gn_stats(const void* __restrict__ x,
                                                float* __restrict__ stats, int b0) {
    bool f32 = detect_f32(x);
    int bg = b0 * NGROUPS + blockIdx.x;      // global (b*32+g)
    int t  = threadIdx.x;
    size_t base = (size_t)bg * (CPG * NPIX);
    float s = 0.f, s2 = 0.f;
    for (int i = t * 8; i < CPG * NPIX; i += 256 * 8) {
        float f[8]; load8v(x, base + i, f32, f);
        #pragma unroll
        for (int e = 0; e < 8; e++) { s += f[e]; s2 += f[e] * f[e]; }
    }
    #pragma unroll
    for (int off = 1; off < 64; off <<= 1) {
        s  += __shfl_xor(s,  off);
        s2 += __shfl_xor(s2, off);
    }
    __shared__ float red[8];
    int w = t >> 6;
    if ((t & 63) == 0) { red[w * 2] = s; red[w * 2 + 1] = s2; }
    __syncthreads();
    if (t == 0) {
        float S  = red[0] + red[2] + red[4] + red[6];
        float S2 = red[1] + red[3] + red[5] + red[7];
        float n  = (float)(CPG * NPIX);
        float mu = S / n;
        float var = S2 / n - mu * mu;
        stats[bg * 2]     = mu;
        stats[bg * 2 + 1] = rsqrtf(var + EPS);
    }
}

// ---------- K2: fused GN-apply + QKV 1x1 conv (NT GEMM) ----------
// qkv[bl][n][o] = sum_c gn(x[bg][c][n]) * qkv_w[o][c] + qkv_b[o]
__global__ __launch_bounds__(256) void qkv_gemm(
    const void* __restrict__ x, const void* __restrict__ gn_w,
    const void* __restrict__ gn_b, const void* __restrict__ qkv_w,
    const void* __restrict__ qkv_b, const float* __restrict__ stats,
    u16* __restrict__ qkv, int b0) {
    bool f32 = detect_f32(x);
    __shared__ float As[16][64];   // [kk][nn]
    __shared__ float Ws[16][64];   // [kk][oo]
    int bl = blockIdx.z, bg = b0 + bl;
    int n0 = blockIdx.x * 64, o0 = blockIdx.y * 64;
    int t  = threadIdx.x;
    int tx = t & 15, ty = t >> 4;
    float acc[4][4] = {};
    int lak = t >> 4, lan = (t & 15) * 4;   // A: kk = lak, nn = lan..lan+3
    int lwo = t >> 2, lwk = (t & 3) * 4;    // W: oo = lwo, kk = lwk..lwk+3

    for (int k0 = 0; k0 < CH; k0 += 16) {
        int c = k0 + lak;
        int g = c >> 3;
        float mu = stats[(bg * NGROUPS + g) * 2];
        float rs = stats[(bg * NGROUPS + g) * 2 + 1];
        float wv = load1(gn_w, c, f32) * rs;
        float bv = load1(gn_b, c, f32) - mu * wv;
        float a[4];
        load4v(x, ((size_t)(bg * CH + c)) * NPIX + n0 + lan, f32, a);
        As[lak][lan + 0] = a[0] * wv + bv;
        As[lak][lan + 1] = a[1] * wv + bv;
        As[lak][lan + 2] = a[2] * wv + bv;
        As[lak][lan + 3] = a[3] * wv + bv;

        float wf[4];
        load4v(qkv_w, (size_t)(o0 + lwo) * CH + k0 + lwk, f32, wf);
        Ws[lwk + 0][lwo] = wf[0]; Ws[lwk + 1][lwo] = wf[1];
        Ws[lwk + 2][lwo] = wf[2]; Ws[lwk + 3][lwo] = wf[3];
        __syncthreads();
        #pragma unroll
        for (int kk = 0; kk < 16; kk++) {
            float4 av = *(const float4*)&As[kk][tx * 4];
            float4 wv4 = *(const float4*)&Ws[kk][ty * 4];
            float aa[4] = {av.x, av.y, av.z, av.w};
            float ww[4] = {wv4.x, wv4.y, wv4.z, wv4.w};
            #pragma unroll
            for (int i = 0; i < 4; i++)
                #pragma unroll
                for (int j = 0; j < 4; j++)
                    acc[i][j] = fmaf(aa[i], ww[j], acc[i][j]);
        }
        __syncthreads();
    }
    float bias[4];
    #pragma unroll
    for (int j = 0; j < 4; j++) bias[j] = load1(qkv_b, o0 + ty * 4 + j, f32);
    #pragma unroll
    for (int i = 0; i < 4; i++) {
        union { uint2 v; u16 s[4]; } pk;
        #pragma unroll
        for (int j = 0; j < 4; j++) pk.s[j] = f2bf(acc[i][j] + bias[j]);
        *(uint2*)(qkv + ((size_t)(bl * NPIX + n0 + tx * 4 + i)) * QKV_O + o0 + ty * 4) = pk.v;
    }
}

// ---------- K3: flash-style attention (ws-internal, always bf16) ----------
__global__ __launch_bounds__(256) void attn(const u16* __restrict__ qkv,
                                            u16* __restrict__ attO) {
    __shared__ u16 Qs[TQ * QSTRIDE];
    __shared__ u16 Ks[TK * QSTRIDE];
    __shared__ u16 Vs[TK * QSTRIDE];
    __shared__ float Ps[TQ * 36];
    int bl = blockIdx.y;
    int q0 = blockIdx.x * TQ;
    int t  = threadIdx.x;
    int r  = t >> 3;
    int q  = t & 7;

    for (int i = t; i < TQ * 32; i += 256) {
        int row = i >> 5, cc = i & 31;
        uint4 u = *(const uint4*)(qkv + ((size_t)(bl * NPIX + q0 + row)) * QKV_O + cc * 8);
        *(uint4*)(Qs + row * QSTRIDE + cc * 8) = u;
    }

    float o[32];
    #pragma unroll
    for (int i = 0; i < 32; i++) o[i] = 0.f;
    float m_i = -1e30f, l_i = 0.f;
    const float scale = 0.0625f;   // 256^-0.5

    for (int kv0 = 0; kv0 < NPIX; kv0 += TK) {
        __syncthreads();   // prev-iter Vs/Ps reads done; Qs stores visible (iter 0)
        for (int i = t; i < TK * 32; i += 256) {
            int row = i >> 5, cc = i & 31;
            const u16* base = qkv + ((size_t)(bl * NPIX + kv0 + row)) * QKV_O;
            *(uint4*)(Ks + row * QSTRIDE + cc * 8) = *(const uint4*)(base + 256 + cc * 8);
            *(uint4*)(Vs + row * QSTRIDE + cc * 8) = *(const uint4*)(base + 512 + cc * 8);
        }
        __syncthreads();

        float s[4] = {0.f, 0.f, 0.f, 0.f};
        for (int c0 = 0; c0 < CH; c0 += 8) {
            uint4 uq = *(const uint4*)(Qs + r * QSTRIDE + c0);
            float qf[8]; unpack8(uq, qf);
            #pragma unroll
            for (int j = 0; j < 4; j++) {
                uint4 uk = *(const uint4*)(Ks + (q + j * 8) * QSTRIDE + c0);
                float kf[8]; unpack8(uk, kf);
                #pragma unroll
                for (int e = 0; e < 8; e++) s[j] = fmaf(qf[e], kf[e], s[j]);
            }
        }
        #pragma unroll
        for (int j = 0; j < 4; j++) s[j] *= scale;

        float mx = fmaxf(fmaxf(s[0], s[1]), fmaxf(s[2], s[3]));
        mx = fmaxf(mx, __shfl_xor(mx, 1, 8));
        mx = fmaxf(mx, __shfl_xor(mx, 2, 8));
        mx = fmaxf(mx, __shfl_xor(mx, 4, 8));
        float m_new = fmaxf(m_i, mx);
        float alpha = __expf(m_i - m_new);
        float p[4], ls = 0.f;
        #pragma unroll
        for (int j = 0; j < 4; j++) { p[j] = __expf(s[j] - m_new); ls += p[j]; }
        ls += __shfl_xor(ls, 1, 8);
        ls += __shfl_xor(ls, 2, 8);
        ls += __shfl_xor(ls, 4, 8);
        l_i = l_i * alpha + ls;
        m_i = m_new;

        #pragma unroll
        for (int j = 0; j < 4; j++) Ps[r * 36 + q + j * 8] = p[j];
        __syncthreads();

        #pragma unroll
        for (int i = 0; i < 32; i++) o[i] *= alpha;
        int cbase = q * 32;
        #pragma unroll 8
        for (int m = 0; m < TK; m++) {
            float pm = Ps[r * 36 + m];
            const u16* vrow = Vs + m * QSTRIDE + cbase;
            #pragma unroll
            for (int cc = 0; cc < 4; cc++) {
                uint4 uv = *(const uint4*)(vrow + cc * 8);
                float vf[8]; unpack8(uv, vf);
                #pragma unroll
                for (int e = 0; e < 8; e++) o[cc * 8 + e] = fmaf(pm, vf[e], o[cc * 8 + e]);
            }
        }
    }

    float inv = 1.0f / l_i;
    u16* op = attO + ((size_t)(bl * NPIX + q0 + r)) * CH + q * 32;
    #pragma unroll
    for (int cc = 0; cc < 4; cc++) {
        union { uint4 v; u16 s[8]; } pk;
        #pragma unroll
        for (int e = 0; e < 8; e++) pk.s[e] = f2bf(o[cc * 8 + e] * inv);
        *(uint4*)(op + cc * 8) = pk.v;
    }
}

// ---------- K4: proj 1x1 conv + residual ----------
__global__ __launch_bounds__(256) void proj_gemm(
    const u16* __restrict__ attO, const void* __restrict__ proj_w,
    const void* __restrict__ proj_b, const void* __restrict__ x,
    void* __restrict__ out, int b0) {
    bool f32 = detect_f32(x);
    __shared__ float As[16][68];   // [kk][nn], padded (transposed store)
    __shared__ float Ws[16][64];   // [kk][oo]
    int bl = blockIdx.z, bg = b0 + bl;
    int n0 = blockIdx.x * 64, o0 = blockIdx.y * 64;
    int t  = threadIdx.x;
    int tx = t & 15, ty = t >> 4;
    float acc[4][4] = {};
    int lan2 = t >> 2, lak2 = (t & 3) * 4;  // A: nn = lan2, kk = lak2..+3
    int lwo = t >> 2,  lwk = (t & 3) * 4;

    for (int k0 = 0; k0 < CH; k0 += 16) {
        uint2 u = *(const uint2*)(attO + ((size_t)(bl * NPIX + n0 + lan2)) * CH + k0 + lak2);
        float a0, a1, a2, a3; unpack2(u.x, a0, a1); unpack2(u.y, a2, a3);
        As[lak2 + 0][lan2] = a0; As[lak2 + 1][lan2] = a1;
        As[lak2 + 2][lan2] = a2; As[lak2 + 3][lan2] = a3;

        float wf[4];
        load4v(proj_w, (size_t)(o0 + lwo) * CH + k0 + lwk, f32, wf);
        Ws[lwk + 0][lwo] = wf[0]; Ws[lwk + 1][lwo] = wf[1];
        Ws[lwk + 2][lwo] = wf[2]; Ws[lwk + 3][lwo] = wf[3];
        __syncthreads();
        #pragma unroll
        for (int kk = 0; kk < 16; kk++) {
            float4 av = *(const float4*)&As[kk][tx * 4];
            float4 wv4 = *(const float4*)&Ws[kk][ty * 4];
            float aa[4] = {av.x, av.y, av.z, av.w};
            float ww[4] = {wv4.x, wv4.y, wv4.z, wv4.w};
            #pragma unroll
            for (int i = 0; i < 4; i++)
                #pragma unroll
                for (int j = 0; j < 4; j++)
                    acc[i][j] = fmaf(aa[i], ww[j], acc[i][j]);
        }
        __syncthreads();
    }
    #pragma unroll
    for (int j = 0; j < 4; j++) {
        float bias = load1(proj_b, o0 + ty * 4 + j, f32);
        size_t off = ((size_t)(bg * CH + o0 + ty * 4 + j)) * NPIX + n0 + tx * 4;
        float rx[4];
        load4v(x, off, f32, rx);
        float fo[4];
        #pragma unroll
        for (int i = 0; i < 4; i++) fo[i] = acc[i][j] + bias + rx[i];
        store4v(out, off, f32, fo);
    }
}

extern "C" void kernel_launch(void* const* d_in, const int* in_sizes, int n_in,
                              void* d_out, int out_size, void* d_ws, size_t ws_size,
                              hipStream_t stream) {
    const void* x      = d_in[0];
    const void* gn_w   = d_in[1];
    const void* gn_b   = d_in[2];
    const void* qkv_w  = d_in[3];
    const void* qkv_b  = d_in[4];
    const void* proj_w = d_in[5];
    const void* proj_b = d_in[6];

    char* ws = (char*)d_ws;
    float* stats = (float*)ws;                           // 128*2 floats (global bg)
    const size_t per_batch = (size_t)NPIX * QKV_O * 2 + (size_t)NPIX * CH * 2; // 8.4 MB
    const size_t need_full = 1024 + BATCH * per_batch;   // 33.6 MB
    int nb = (ws_size >= need_full) ? BATCH : 1;         // constant across calls -> graph-safe

    u16* qkv  = (u16*)(ws + 1024);
    u16* attO = (u16*)(ws + 1024 + (size_t)nb * NPIX * QKV_O * 2);

    for (int b0 = 0; b0 < BATCH; b0 += nb) {
        gn_stats<<<dim3(nb * NGROUPS), 256, 0, stream>>>(x, stats, b0);
        qkv_gemm<<<dim3(NPIX / 64, QKV_O / 64, nb), 256, 0, stream>>>(
            x, gn_w, gn_b, qkv_w, qkv_b, stats, qkv, b0);
        attn<<<dim3(NPIX / TQ, nb), 256, 0, stream>>>(qkv, attO);
        proj_gemm<<<dim3(NPIX / 64, CH / 64, nb), 256, 0, stream>>>(
            attO, proj_w, proj_b, x, d_out, b0);
    }
}

// Round 3
// 937.892 us; speedup vs baseline: 2.3332x; 2.3332x over previous
//
#include <hip/hip_runtime.h>
#include <stdint.h>

typedef unsigned short u16;
typedef __attribute__((ext_vector_type(8))) short bf16x8;   // 8 bf16 = 4 VGPRs
typedef __attribute__((ext_vector_type(4))) float f32x4;

#define BATCH   4
#define CH      256
#define NPIX    4096      // 64*64
#define NGROUPS 32
#define CPG     8
#define EPS     1e-5f

// attention tiles
#define ATQ   32          // Q rows per block (2 waves x 16)
#define ATK   32          // KV rows per tile
#define KSTR  264         // K LDS row stride (elems): 2-way bank alias only
#define VSTR  40          // Vt LDS row stride
#define PSTR  40          // P LDS row stride

// ---------- bf16 helpers ----------
__device__ __forceinline__ float bf2f(u16 u) {
    union { uint32_t i; float f; } v; v.i = ((uint32_t)u) << 16; return v.f;
}
__device__ __forceinline__ u16 f2bf(float f) {
    union { float f; uint32_t i; } v; v.f = f;
    uint32_t x = v.i;
    uint32_t r = (x + 0x7fffu + ((x >> 16) & 1u)) >> 16;
    return (u16)r;
}
__device__ __forceinline__ void unpack2(uint32_t u, float& a, float& b) {
    union { uint32_t i; float f; } lo, hi;
    lo.i = u << 16; hi.i = u & 0xffff0000u;
    a = lo.f; b = hi.f;
}
__device__ __forceinline__ void unpack8(uint4 u, float* f) {
    unpack2(u.x, f[0], f[1]); unpack2(u.y, f[2], f[3]);
    unpack2(u.z, f[4], f[5]); unpack2(u.w, f[6], f[7]);
}

// ---------- runtime input-dtype detection (harness dtype unknown: fp32 vs bf16) ----------
__device__ __forceinline__ bool detect_f32(const void* xv) {
    const u16* p = (const u16*)xv;
    int bad = 0;
    #pragma unroll
    for (int i = 0; i < 32; i++) {
        u16 v = p[2 * i];
        int e = (v >> 7) & 0xff;
        bad += (e < 0x68 || e > 0x90) ? 1 : 0;
    }
    return bad >= 10;
}
__device__ __forceinline__ float load1(const void* b, size_t i, bool f32) {
    return f32 ? ((const float*)b)[i] : bf2f(((const u16*)b)[i]);
}
__device__ __forceinline__ void load4v(const void* base, size_t off, bool f32, float* f) {
    if (f32) {
        float4 a = *(const float4*)((const float*)base + off);
        f[0] = a.x; f[1] = a.y; f[2] = a.z; f[3] = a.w;
    } else {
        uint2 u = *(const uint2*)((const u16*)base + off);
        unpack2(u.x, f[0], f[1]); unpack2(u.y, f[2], f[3]);
    }
}
__device__ __forceinline__ void load8v(const void* base, size_t off, bool f32, float* f) {
    if (f32) {
        const float4* p = (const float4*)((const float*)base + off);
        float4 a = p[0], b = p[1];
        f[0] = a.x; f[1] = a.y; f[2] = a.z; f[3] = a.w;
        f[4] = b.x; f[5] = b.y; f[6] = b.z; f[7] = b.w;
    } else {
        uint4 u = *(const uint4*)((const u16*)base + off);
        unpack8(u, f);
    }
}
__device__ __forceinline__ void store4v(void* base, size_t off, bool f32, const float* f) {
    if (f32) {
        *(float4*)((float*)base + off) = make_float4(f[0], f[1], f[2], f[3]);
    } else {
        union { uint2 v; u16 s[4]; } pk;
        #pragma unroll
        for (int j = 0; j < 4; j++) pk.s[j] = f2bf(f[j]);
        *(uint2*)((u16*)base + off) = pk.v;
    }
}

// ---------- K1: GroupNorm stats ----------
__global__ __launch_bounds__(256) void gn_stats(const void* __restrict__ x,
                                                float* __restrict__ stats, int b0) {
    bool f32 = detect_f32(x);
    int bg = b0 * NGROUPS + blockIdx.x;
    int t  = threadIdx.x;
    size_t base = (size_t)bg * (CPG * NPIX);
    float s = 0.f, s2 = 0.f;
    for (int i = t * 8; i < CPG * NPIX; i += 256 * 8) {
        float f[8]; load8v(x, base + i, f32, f);
        #pragma unroll
        for (int e = 0; e < 8; e++) { s += f[e]; s2 += f[e] * f[e]; }
    }
    #pragma unroll
    for (int off = 1; off < 64; off <<= 1) {
        s  += __shfl_xor(s,  off);
        s2 += __shfl_xor(s2, off);
    }
    __shared__ float red[8];
    int w = t >> 6;
    if ((t & 63) == 0) { red[w * 2] = s; red[w * 2 + 1] = s2; }
    __syncthreads();
    if (t == 0) {
        float S  = red[0] + red[2] + red[4] + red[6];
        float S2 = red[1] + red[3] + red[5] + red[7];
        float n  = (float)(CPG * NPIX);
        float mu = S / n;
        float var = S2 / n - mu * mu;
        stats[bg * 2]     = mu;
        stats[bg * 2 + 1] = rsqrtf(var + EPS);
    }
}

// ---------- K2: fused GN-apply + QKV 1x1 conv ----------
// Q,K -> qk[bl][n][0..511]; V -> vt[bl][c][n] (pre-transposed for attention)
__global__ __launch_bounds__(256) void qkv_gemm(
    const void* __restrict__ x, const void* __restrict__ gn_w,
    const void* __restrict__ gn_b, const void* __restrict__ qkv_w,
    const void* __restrict__ qkv_b, const float* __restrict__ stats,
    u16* __restrict__ qk, u16* __restrict__ vt, int b0) {
    bool f32 = detect_f32(x);
    __shared__ float As[16][64];
    __shared__ float Ws[16][64];
    int bl = blockIdx.z, bg = b0 + bl;
    int n0 = blockIdx.x * 64, o0 = blockIdx.y * 64;
    int t  = threadIdx.x;
    int tx = t & 15, ty = t >> 4;
    float acc[4][4] = {};
    int lak = t >> 4, lan = (t & 15) * 4;
    int lwo = t >> 2, lwk = (t & 3) * 4;

    for (int k0 = 0; k0 < CH; k0 += 16) {
        int c = k0 + lak;
        int g = c >> 3;
        float mu = stats[(bg * NGROUPS + g) * 2];
        float rs = stats[(bg * NGROUPS + g) * 2 + 1];
        float wv = load1(gn_w, c, f32) * rs;
        float bv = load1(gn_b, c, f32) - mu * wv;
        float a[4];
        load4v(x, ((size_t)(bg * CH + c)) * NPIX + n0 + lan, f32, a);
        As[lak][lan + 0] = a[0] * wv + bv;
        As[lak][lan + 1] = a[1] * wv + bv;
        As[lak][lan + 2] = a[2] * wv + bv;
        As[lak][lan + 3] = a[3] * wv + bv;

        float wf[4];
        load4v(qkv_w, (size_t)(o0 + lwo) * CH + k0 + lwk, f32, wf);
        Ws[lwk + 0][lwo] = wf[0]; Ws[lwk + 1][lwo] = wf[1];
        Ws[lwk + 2][lwo] = wf[2]; Ws[lwk + 3][lwo] = wf[3];
        __syncthreads();
        #pragma unroll
        for (int kk = 0; kk < 16; kk++) {
            float4 av = *(const float4*)&As[kk][tx * 4];
            float4 wv4 = *(const float4*)&Ws[kk][ty * 4];
            float aa[4] = {av.x, av.y, av.z, av.w};
            float ww[4] = {wv4.x, wv4.y, wv4.z, wv4.w};
            #pragma unroll
            for (int i = 0; i < 4; i++)
                #pragma unroll
                for (int j = 0; j < 4; j++)
                    acc[i][j] = fmaf(aa[i], ww[j], acc[i][j]);
        }
        __syncthreads();
    }
    float bias[4];
    #pragma unroll
    for (int j = 0; j < 4; j++) bias[j] = load1(qkv_b, o0 + ty * 4 + j, f32);
    if (o0 < 512) {
        // Q/K: token-major rows of 512
        #pragma unroll
        for (int i = 0; i < 4; i++) {
            union { uint2 v; u16 s[4]; } pk;
            #pragma unroll
            for (int j = 0; j < 4; j++) pk.s[j] = f2bf(acc[i][j] + bias[j]);
            *(uint2*)(qk + ((size_t)(bl * NPIX + n0 + tx * 4 + i)) * 512 + o0 + ty * 4) = pk.v;
        }
    } else {
        // V transposed: vt[c][n]
        int c0 = o0 - 512 + ty * 4;
        #pragma unroll
        for (int j = 0; j < 4; j++) {
            union { uint2 v; u16 s[4]; } pk;
            #pragma unroll
            for (int i = 0; i < 4; i++) pk.s[i] = f2bf(acc[i][j] + bias[j]);
            *(uint2*)(vt + ((size_t)(bl * CH + c0 + j)) * NPIX + n0 + tx * 4) = pk.v;
        }
    }
}

// ---------- K3: MFMA flash attention ----------
// 2 waves/block; wave w owns Q rows q0+16w..+15 (Q frags in VGPRs).
// S = Q.K^T via mfma_16x16x32; online softmax in C-layout; P->LDS (A-layout
// round trip, m120 pattern); O += P.V with V^T staged from vt.
__global__ __launch_bounds__(128) void attn_mfma(const u16* __restrict__ qk,
                                                 const u16* __restrict__ vt,
                                                 u16* __restrict__ attO) {
    __shared__ u16 Ks[ATK * KSTR];       // 16.9 KB
    __shared__ u16 Vts[CH * VSTR];       // 20.5 KB
    __shared__ u16 Ps[2][16 * PSTR];     // 2.6 KB (wave-private halves)
    int bl   = blockIdx.y;
    int q0   = blockIdx.x * ATQ;
    int t    = threadIdx.x;
    int w    = t >> 6;
    int lane = t & 63;
    int l15  = lane & 15;
    int quad = lane >> 4;

    const u16* qkb = qk + (size_t)bl * NPIX * 512;
    const u16* vtb = vt + (size_t)bl * CH * NPIX;

    // Q fragments: A[m=l15][k=kc*32+quad*8+j]
    bf16x8 qf[8];
    {
        const u16* qrow = qkb + (size_t)(q0 + 16 * w + l15) * 512;
        #pragma unroll
        for (int kc = 0; kc < 8; kc++)
            qf[kc] = *(const bf16x8*)(qrow + kc * 32 + quad * 8);
    }
    f32x4 o[16];
    #pragma unroll
    for (int i = 0; i < 16; i++) o[i] = (f32x4){0.f, 0.f, 0.f, 0.f};
    float m_r[4] = {-3e38f, -3e38f, -3e38f, -3e38f};
    float l_r[4] = {0.f, 0.f, 0.f, 0.f};
    const float scale = 0.0625f;

    for (int kv0 = 0; kv0 < NPIX; kv0 += ATK) {
        __syncthreads();
        // stage K tile: 32 rows x 256
        #pragma unroll
        for (int i = 0; i < 8; i++) {
            int e = t + i * 128;
            int row = e >> 5, ch = e & 31;
            *(uint4*)(Ks + row * KSTR + ch * 8) =
                *(const uint4*)(qkb + (size_t)(kv0 + row) * 512 + 256 + ch * 8);
        }
        // stage V^T tile: 256 rows x 32
        #pragma unroll
        for (int i = 0; i < 8; i++) {
            int e = t + i * 128;
            int row = e >> 2, ch = e & 3;
            *(uint4*)(Vts + row * VSTR + ch * 8) =
                *(const uint4*)(vtb + (size_t)row * NPIX + kv0 + ch * 8);
        }
        __syncthreads();

        // S tiles (16 x 32): B[k][n]=K[n=nt*16+l15][k] -> ds_read_b128
        f32x4 s0 = (f32x4){0.f, 0.f, 0.f, 0.f};
        f32x4 s1 = (f32x4){0.f, 0.f, 0.f, 0.f};
        #pragma unroll
        for (int kc = 0; kc < 8; kc++) {
            bf16x8 b0 = *(const bf16x8*)(Ks + l15 * KSTR + kc * 32 + quad * 8);
            bf16x8 b1 = *(const bf16x8*)(Ks + (16 + l15) * KSTR + kc * 32 + quad * 8);
            s0 = __builtin_amdgcn_mfma_f32_16x16x32_bf16(qf[kc], b0, s0, 0, 0, 0);
            s1 = __builtin_amdgcn_mfma_f32_16x16x32_bf16(qf[kc], b1, s1, 0, 0, 0);
        }

        // online softmax per C-layout row (row = quad*4+r, cols spread over 16 lanes)
        float alpha[4];
        #pragma unroll
        for (int r = 0; r < 4; r++) {
            float sv0 = s0[r] * scale, sv1 = s1[r] * scale;
            float mx = fmaxf(sv0, sv1);
            mx = fmaxf(mx, __shfl_xor(mx, 1));
            mx = fmaxf(mx, __shfl_xor(mx, 2));
            mx = fmaxf(mx, __shfl_xor(mx, 4));
            mx = fmaxf(mx, __shfl_xor(mx, 8));
            float mn = fmaxf(m_r[r], mx);
            alpha[r] = __expf(m_r[r] - mn);
            float p0 = __expf(sv0 - mn), p1 = __expf(sv1 - mn);
            float ls = p0 + p1;
            ls += __shfl_xor(ls, 1);
            ls += __shfl_xor(ls, 2);
            ls += __shfl_xor(ls, 4);
            ls += __shfl_xor(ls, 8);
            l_r[r] = l_r[r] * alpha[r] + ls;
            m_r[r] = mn;
            Ps[w][(quad * 4 + r) * PSTR + l15]      = f2bf(p0);
            Ps[w][(quad * 4 + r) * PSTR + 16 + l15] = f2bf(p1);
        }

        // rescale O
        #pragma unroll
        for (int dt = 0; dt < 16; dt++) {
            f32x4 t4 = o[dt];
            t4[0] *= alpha[0]; t4[1] *= alpha[1];
            t4[2] *= alpha[2]; t4[3] *= alpha[3];
            o[dt] = t4;
        }

        // PV: A = P (A-layout read from wave-private LDS), B = V[k=m][n=d] from Vts
        bf16x8 pf = *(const bf16x8*)(&Ps[w][l15 * PSTR + quad * 8]);
        #pragma unroll
        for (int dt = 0; dt < 16; dt++) {
            bf16x8 vf = *(const bf16x8*)(Vts + (dt * 16 + l15) * VSTR + quad * 8);
            o[dt] = __builtin_amdgcn_mfma_f32_16x16x32_bf16(pf, vf, o[dt], 0, 0, 0);
        }
    }

    float inv[4];
    #pragma unroll
    for (int r = 0; r < 4; r++) inv[r] = 1.0f / l_r[r];
    u16* ob = attO + ((size_t)(bl * NPIX + q0 + 16 * w)) * CH;
    #pragma unroll
    for (int dt = 0; dt < 16; dt++)
        #pragma unroll
        for (int r = 0; r < 4; r++)
            ob[(quad * 4 + r) * CH + dt * 16 + l15] = f2bf(o[dt][r] * inv[r]);
}

// ---------- K4: proj 1x1 conv + residual ----------
__global__ __launch_bounds__(256) void proj_gemm(
    const u16* __restrict__ attO, const void* __restrict__ proj_w,
    const void* __restrict__ proj_b, const void* __restrict__ x,
    void* __restrict__ out, int b0) {
    bool f32 = detect_f32(x);
    __shared__ float As[16][68];
    __shared__ float Ws[16][64];
    int bl = blockIdx.z, bg = b0 + bl;
    int n0 = blockIdx.x * 64, o0 = blockIdx.y * 64;
    int t  = threadIdx.x;
    int tx = t & 15, ty = t >> 4;
    float acc[4][4] = {};
    int lan2 = t >> 2, lak2 = (t & 3) * 4;
    int lwo = t >> 2,  lwk = (t & 3) * 4;

    for (int k0 = 0; k0 < CH; k0 += 16) {
        uint2 u = *(const uint2*)(attO + ((size_t)(bl * NPIX + n0 + lan2)) * CH + k0 + lak2);
        float a0, a1, a2, a3; unpack2(u.x, a0, a1); unpack2(u.y, a2, a3);
        As[lak2 + 0][lan2] = a0; As[lak2 + 1][lan2] = a1;
        As[lak2 + 2][lan2] = a2; As[lak2 + 3][lan2] = a3;

        float wf[4];
        load4v(proj_w, (size_t)(o0 + lwo) * CH + k0 + lwk, f32, wf);
        Ws[lwk + 0][lwo] = wf[0]; Ws[lwk + 1][lwo] = wf[1];
        Ws[lwk + 2][lwo] = wf[2]; Ws[lwk + 3][lwo] = wf[3];
        __syncthreads();
        #pragma unroll
        for (int kk = 0; kk < 16; kk++) {
            float4 av = *(const float4*)&As[kk][tx * 4];
            float4 wv4 = *(const float4*)&Ws[kk][ty * 4];
            float aa[4] = {av.x, av.y, av.z, av.w};
            float ww[4] = {wv4.x, wv4.y, wv4.z, wv4.w};
            #pragma unroll
            for (int i = 0; i < 4; i++)
                #pragma unroll
                for (int j = 0; j < 4; j++)
                    acc[i][j] = fmaf(aa[i], ww[j], acc[i][j]);
        }
        __syncthreads();
    }
    #pragma unroll
    for (int j = 0; j < 4; j++) {
        float bias = load1(proj_b, o0 + ty * 4 + j, f32);
        size_t off = ((size_t)(bg * CH + o0 + ty * 4 + j)) * NPIX + n0 + tx * 4;
        float rx[4];
        load4v(x, off, f32, rx);
        float fo[4];
        #pragma unroll
        for (int i = 0; i < 4; i++) fo[i] = acc[i][j] + bias + rx[i];
        store4v(out, off, f32, fo);
    }
}

extern "C" void kernel_launch(void* const* d_in, const int* in_sizes, int n_in,
                              void* d_out, int out_size, void* d_ws, size_t ws_size,
                              hipStream_t stream) {
    const void* x      = d_in[0];
    const void* gn_w   = d_in[1];
    const void* gn_b   = d_in[2];
    const void* qkv_w  = d_in[3];
    const void* qkv_b  = d_in[4];
    const void* proj_w = d_in[5];
    const void* proj_b = d_in[6];

    char* ws = (char*)d_ws;
    float* stats = (float*)ws;
    // per batch: qk 4 MB + vt 2 MB + attO 2 MB = 8.39 MB (same footprint as R2)
    const size_t per_batch = (size_t)NPIX * 512 * 2 + (size_t)CH * NPIX * 2 + (size_t)NPIX * CH * 2;
    const size_t need_full = 1024 + BATCH * per_batch;   // 33.56 MB (known to fit)
    int nb = (ws_size >= need_full) ? BATCH : 1;

    u16* qk   = (u16*)(ws + 1024);
    u16* vt   = qk + (size_t)nb * NPIX * 512;
    u16* attO = vt + (size_t)nb * CH * NPIX;

    for (int b0 = 0; b0 < BATCH; b0 += nb) {
        gn_stats<<<dim3(nb * NGROUPS), 256, 0, stream>>>(x, stats, b0);
        qkv_gemm<<<dim3(NPIX / 64, 768 / 64, nb), 256, 0, stream>>>(
            x, gn_w, gn_b, qkv_w, qkv_b, stats, qk, vt, b0);
        attn_mfma<<<dim3(NPIX / ATQ, nb), 128, 0, stream>>>(qk, vt, attO);
        proj_gemm<<<dim3(NPIX / 64, CH / 64, nb), 256, 0, stream>>>(
            attO, proj_w, proj_b, x, d_out, b0);
    }
}